// Round 1
// baseline (409.657 us; speedup 1.0000x reference)
//
#include <hip/hip_runtime.h>

#define DD 128
#define NN 512
#define NODES 1024
#define TILE 32

__device__ __forceinline__ float sigmoidf_(float x) { return 1.f / (1.f + __expf(-x)); }
__device__ __forceinline__ float siluf_(float x)    { return x / (1.f + __expf(-x)); }

__device__ __forceinline__ unsigned short f2bf_(float v) {
  unsigned int u = __float_as_uint(v);
  u += 0x7fffu + ((u >> 16) & 1u);   // round-to-nearest-even
  return (unsigned short)(u >> 16);
}

// ---------------- prep kernel: per-node terms + folded weights ----------------
__global__ __launch_bounds__(128) void prep_kernel(
    const float* __restrict__ sf, const float* __restrict__ cons,
    const float* __restrict__ eW1, const float* __restrict__ eb1,
    const float* __restrict__ eW2, const float* __restrict__ eb2,
    const float* __restrict__ vW1, const float* __restrict__ vb1,
    float* __restrict__ Ag, float* __restrict__ Bvg,
    float* __restrict__ E2V1, float* __restrict__ m2,
    float* __restrict__ c1, float* __restrict__ mb)
{
  const int bid = blockIdx.x;
  const int d = threadIdx.x;
  if (bid < NODES) {
    // A[node,d] = sum_k sf[node,k]*eW1[128+k,d] + cons*eW1[258,d]
    // Bv[node,d] = sum_k sf[node,k]*eW1[k,d]    + cons*eW1[257,d] + eb1[d]
    float c = cons[bid];
    float aacc = c * eW1[258*DD + d];
    float bacc = eb1[d] + c * eW1[257*DD + d];
    const float* sfrow = sf + bid*DD;
    #pragma unroll 4
    for (int k = 0; k < DD; ++k) {
      float s = sfrow[k];
      aacc = fmaf(s, eW1[(128+k)*DD + d], aacc);
      bacc = fmaf(s, eW1[k*DD + d], bacc);
    }
    Ag[bid*DD + d]  = aacc;
    Bvg[bid*DD + d] = bacc;
  } else if (bid < NODES + 128) {
    // E2V1[k,d] = sum_t eW2[k,t]*vW1[t,d];  m2[k] = mean_d eW2[k,d]
    const int k = bid - NODES;
    float acc = 0.f;
    #pragma unroll 4
    for (int t = 0; t < DD; ++t) acc = fmaf(eW2[k*DD + t], vW1[t*DD + d], acc);
    E2V1[k*DD + d] = acc;
    if (d == 0) {
      float s = 0.f;
      for (int t = 0; t < DD; ++t) s += eW2[k*DD + t];
      m2[k] = s * (1.0f/128.0f);
    }
  } else {
    // c1[d] = vb1[d] + sum_k eb2[k]*vW1[k,d];  mb = mean(eb2)
    float acc = vb1[d];
    #pragma unroll 4
    for (int k = 0; k < DD; ++k) acc = fmaf(eb2[k], vW1[k*DD + d], acc);
    c1[d] = acc;
    if (d == 0) {
      float s = 0.f;
      for (int k = 0; k < DD; ++k) s += eb2[k];
      mb[0] = s * (1.0f/128.0f);
    }
  }
}

// ---------------- main kernel: one block per (b,i) row ----------------
__global__ __launch_bounds__(256) void edge_kernel(
    const float* __restrict__ sf, const float* __restrict__ vf,
    const float* __restrict__ pos, const float* __restrict__ pm,
    const float* __restrict__ eW1,
    const float* __restrict__ eW2, const float* __restrict__ eb2,
    const float* __restrict__ sW1, const float* __restrict__ sb1,
    const float* __restrict__ sW2, const float* __restrict__ sb2,
    const float* __restrict__ vW2g, const float* __restrict__ vb2g,
    const float* __restrict__ lnw, const float* __restrict__ lnb,
    const float* __restrict__ Ag, const float* __restrict__ Bvg,
    const float* __restrict__ E2V1g, const float* __restrict__ m2g,
    const float* __restrict__ c1g, const float* __restrict__ mbg,
    float* __restrict__ sout, float* __restrict__ vout, float* __restrict__ ewout)
{
  __shared__ __align__(16) unsigned short e2v1s[128][128]; // bf16, 32 KB
  __shared__ float hT[TILE][132];                          // silu(pre) tile, padded
  __shared__ float BvL[DD], w256L[DD], w259L[DD], m2L[DD];
  __shared__ float distA[TILE], maskA[TILE], wA[TILE], gA[TILE];
  __shared__ float dirA[TILE][3];
  __shared__ float posi[3];
  __shared__ float swL[32];
  __shared__ float vmL[96];
  __shared__ float redA[2], redB[2];
  __shared__ float miscS[1];

  const int tid = threadIdx.x;
  const int ni  = blockIdx.x;            // b*512 + i
  const int nb  = (ni >> 9) << 9;        // batch base node

  // stage E2V1 into LDS as bf16
  for (int e = tid; e < 128*128; e += 256) {
    e2v1s[e >> 7][e & 127] = f2bf_(E2V1g[e]);
  }
  if (tid < 128) {
    BvL[tid]   = Bvg[ni*DD + tid];
    w256L[tid] = eW1[256*DD + tid];
    w259L[tid] = eW1[259*DD + tid];
    m2L[tid]   = m2g[tid];
  }
  if (tid < 3) posi[tid] = pos[ni*3 + tid];

  const int dt = tid & 15, jt = tid >> 4;
  float c1r[8], vw2r[8];
  #pragma unroll
  for (int m = 0; m < 8; ++m) { c1r[m] = c1g[dt*8 + m]; vw2r[m] = vW2g[dt*8 + m]; }
  const float mbv = mbg[0], vb2v = vb2g[0];
  const int d = tid & 127, sub = tid >> 7;
  const int jl3 = tid / 3, c3 = tid - 3*(tid/3);

  float Sreg = 0.f, swpart = 0.f, vmreg = 0.f;
  __syncthreads();

  for (int tile = 0; tile < 16; ++tile) {
    const int jt0 = tile * TILE;
    // A0: geometry + mask for 32 j's
    if (tid < TILE) {
      int j = jt0 + tid;
      float rx = posi[0] - pos[(nb + j)*3 + 0];
      float ry = posi[1] - pos[(nb + j)*3 + 1];
      float rz = posi[2] - pos[(nb + j)*3 + 2];
      float dist = fmaxf(sqrtf(rx*rx + ry*ry + rz*rz), 1e-8f);
      distA[tid] = dist;
      float inv = 1.f / dist;
      dirA[tid][0] = rx*inv; dirA[tid][1] = ry*inv; dirA[tid][2] = rz*inv;
      maskA[tid] = pm[ni*NN + j];
    }
    __syncthreads();
    // A1: h = silu(Bv_i + A_j + dist*w256 + mask*w259)
    #pragma unroll
    for (int it = 0; it < 16; ++it) {
      int e = tid + it*256;
      int j = e >> 7, dd2 = e & 127;
      float pre = BvL[dd2] + Ag[(nb + jt0 + j)*DD + dd2]
                + distA[j]*w256L[dd2] + maskA[j]*w259L[dd2];
      hT[j][dd2] = siluf_(pre);
    }
    __syncthreads();
    // A2: edge weight w = sigmoid(h.m2 + mb) * mask
    {
      int jl = tid >> 3, part = tid & 7;
      float psum = 0.f;
      #pragma unroll
      for (int t = 0; t < 16; ++t) psum = fmaf(hT[jl][part*16 + t], m2L[part*16 + t], psum);
      psum += __shfl_xor(psum, 1);
      psum += __shfl_xor(psum, 2);
      psum += __shfl_xor(psum, 4);
      if (part == 0) {
        float w = maskA[jl] * sigmoidf_(psum + mbv);
        wA[jl] = w;
        ewout[ni*NN + jt0 + jl] = w;
        swpart += w;
      }
    }
    __syncthreads();
    // A3: S[d] += sum_j w[j]*h[j][d] (partial per sub)
    #pragma unroll
    for (int r = 0; r < 16; ++r) {
      int j = sub*16 + r;
      Sreg = fmaf(wA[j], hT[j][d], Sreg);
    }
    // B: G1pre[j][d] = sum_k h[j][k]*E2V1[k][d]  (thread: 2 j's x 8 d's)
    float acc0[8], acc1[8];
    #pragma unroll
    for (int m = 0; m < 8; ++m) { acc0[m] = 0.f; acc1[m] = 0.f; }
    const unsigned short* erow = &e2v1s[0][dt*8];
    #pragma unroll 4
    for (int k = 0; k < 128; ++k) {
      uint4 rv = *(const uint4*)(erow + (size_t)k*128);
      float h0 = hT[jt][k], h1 = hT[jt + 16][k];
      float cc;
      cc = __uint_as_float(rv.x << 16);          acc0[0]=fmaf(h0,cc,acc0[0]); acc1[0]=fmaf(h1,cc,acc1[0]);
      cc = __uint_as_float(rv.x & 0xffff0000u);  acc0[1]=fmaf(h0,cc,acc0[1]); acc1[1]=fmaf(h1,cc,acc1[1]);
      cc = __uint_as_float(rv.y << 16);          acc0[2]=fmaf(h0,cc,acc0[2]); acc1[2]=fmaf(h1,cc,acc1[2]);
      cc = __uint_as_float(rv.y & 0xffff0000u);  acc0[3]=fmaf(h0,cc,acc0[3]); acc1[3]=fmaf(h1,cc,acc1[3]);
      cc = __uint_as_float(rv.z << 16);          acc0[4]=fmaf(h0,cc,acc0[4]); acc1[4]=fmaf(h1,cc,acc1[4]);
      cc = __uint_as_float(rv.z & 0xffff0000u);  acc0[5]=fmaf(h0,cc,acc0[5]); acc1[5]=fmaf(h1,cc,acc1[5]);
      cc = __uint_as_float(rv.w << 16);          acc0[6]=fmaf(h0,cc,acc0[6]); acc1[6]=fmaf(h1,cc,acc1[6]);
      cc = __uint_as_float(rv.w & 0xffff0000u);  acc0[7]=fmaf(h0,cc,acc0[7]); acc1[7]=fmaf(h1,cc,acc1[7]);
    }
    // gate = (sum_d silu(G1pre+c1)*vW2 + vb2) * w
    float pg0 = 0.f, pg1 = 0.f;
    #pragma unroll
    for (int m = 0; m < 8; ++m) {
      float g0 = siluf_(acc0[m] + c1r[m]); pg0 = fmaf(g0, vw2r[m], pg0);
      float g1 = siluf_(acc1[m] + c1r[m]); pg1 = fmaf(g1, vw2r[m], pg1);
    }
    #pragma unroll
    for (int off = 1; off < 16; off <<= 1) {
      pg0 += __shfl_xor(pg0, off);
      pg1 += __shfl_xor(pg1, off);
    }
    if (dt == 0) {
      gA[jt]      = (pg0 + vb2v) * wA[jt];
      gA[jt + 16] = (pg1 + vb2v) * wA[jt + 16];
    }
    __syncthreads();
    // B2: vector message partials
    if (tid < 96) vmreg = fmaf(gA[jl3], dirA[jl3][c3], vmreg);
    __syncthreads();
  }

  // -------- epilogue (hT no longer needed; alias rows as scratch) --------
  float* SL    = &hT[0][0];
  float* partA = &hT[1][0];
  float* msgL  = &hT[2][0];
  float* u1L   = &hT[3][0];
  float* xoL   = &hT[4][0];

  if (sub == 0) SL[d] = Sreg;
  if ((tid & 7) == 0) swL[tid >> 3] = swpart;
  if (tid < 96) vmL[tid] = vmreg;
  __syncthreads();
  if (sub == 1) SL[d] += Sreg;
  if (tid == 0) { float s = 0.f; for (int t = 0; t < 32; ++t) s += swL[t]; miscS[0] = s; }
  if (tid < 3) {
    float s = 0.f;
    #pragma unroll
    for (int jl = 0; jl < 32; ++jl) s += vmL[jl*3 + tid];
    vout[ni*3 + tid] = vf[ni*3 + tid] + s;
  }
  __syncthreads();
  const float sumwv = miscS[0];

  // message_scalar = S@eW2 + sumw*eb2
  float p = 0.f;
  { int k0 = sub*64;
    #pragma unroll 4
    for (int k = k0; k < k0 + 64; ++k) p = fmaf(SL[k], eW2[k*DD + d], p); }
  if (sub) partA[d] = p;
  __syncthreads();
  if (!sub) msgL[d] = p + partA[d] + sumwv * eb2[d];
  __syncthreads();

  // u1 = silu([x, msg] @ sW1 + sb1)
  float q = 0.f;
  if (!sub) {
    const float* xr = sf + ni*DD;
    #pragma unroll 4
    for (int t = 0; t < 128; ++t) q = fmaf(xr[t], sW1[t*DD + d], q);
  } else {
    #pragma unroll 4
    for (int t = 0; t < 128; ++t) q = fmaf(msgL[t], sW1[(128 + t)*DD + d], q);
  }
  if (sub) partA[d] = q;
  __syncthreads();
  if (!sub) { float u = q + partA[d] + sb1[d]; u1L[d] = siluf_(u); }
  __syncthreads();

  // upd = u1 @ sW2 + sb2; x = sf + upd
  float r2 = 0.f;
  { int t0 = sub*64;
    #pragma unroll 4
    for (int t = t0; t < t0 + 64; ++t) r2 = fmaf(u1L[t], sW2[t*DD + d], r2); }
  if (sub) partA[d] = r2;
  __syncthreads();
  if (!sub) xoL[d] = sf[ni*DD + d] + r2 + partA[d] + sb2[d];
  __syncthreads();

  // LayerNorm
  if (tid < 128) {
    float v = xoL[tid];
    float s1 = v, s2 = v*v;
    #pragma unroll
    for (int off = 1; off < 64; off <<= 1) { s1 += __shfl_xor(s1, off); s2 += __shfl_xor(s2, off); }
    if ((tid & 63) == 0) { redA[tid >> 6] = s1; redB[tid >> 6] = s2; }
  }
  __syncthreads();
  if (tid < 128) {
    float s1 = redA[0] + redA[1], s2 = redB[0] + redB[1];
    float mu = s1 * 0.0078125f;
    float var = s2 * 0.0078125f - mu*mu;
    sout[ni*DD + tid] = (xoL[tid] - mu) * rsqrtf(var + 1e-5f) * lnw[tid] + lnb[tid];
  }
}

extern "C" void kernel_launch(void* const* d_in, const int* in_sizes, int n_in,
                              void* d_out, int out_size, void* d_ws, size_t ws_size,
                              hipStream_t stream) {
  const float* sf   = (const float*)d_in[0];
  const float* vf   = (const float*)d_in[1];
  const float* pos  = (const float*)d_in[2];
  const float* pm   = (const float*)d_in[3];
  const float* cons = (const float*)d_in[4];
  const float* eW1  = (const float*)d_in[5];
  const float* eb1  = (const float*)d_in[6];
  const float* eW2  = (const float*)d_in[7];
  const float* eb2  = (const float*)d_in[8];
  const float* sW1  = (const float*)d_in[9];
  const float* sb1  = (const float*)d_in[10];
  const float* sW2  = (const float*)d_in[11];
  const float* sb2  = (const float*)d_in[12];
  const float* vW1  = (const float*)d_in[13];
  const float* vb1  = (const float*)d_in[14];
  const float* vW2  = (const float*)d_in[15];
  const float* vb2  = (const float*)d_in[16];
  const float* lnw  = (const float*)d_in[17];
  const float* lnb  = (const float*)d_in[18];

  float* ws   = (float*)d_ws;
  float* Ag   = ws;                 // 1024*128
  float* Bvg  = ws + 131072;        // 1024*128
  float* E2V1 = ws + 262144;        // 128*128
  float* m2   = ws + 278528;        // 128
  float* c1   = ws + 278656;        // 128
  float* mb   = ws + 278784;        // 1

  float* sout  = (float*)d_out;     // [2,512,128]
  float* vout  = sout + 131072;     // [2,512,3]
  float* ewout = sout + 134144;     // [2,512,512]

  hipLaunchKernelGGL(prep_kernel, dim3(NODES + 129), dim3(128), 0, stream,
                     sf, cons, eW1, eb1, eW2, eb2, vW1, vb1,
                     Ag, Bvg, E2V1, m2, c1, mb);
  hipLaunchKernelGGL(edge_kernel, dim3(NODES), dim3(256), 0, stream,
                     sf, vf, pos, pm, eW1, eW2, eb2, sW1, sb1, sW2, sb2,
                     vW2, vb2, lnw, lnb, Ag, Bvg, E2V1, m2, c1, mb,
                     sout, vout, ewout);
}

// Round 2
// 174.901 us; speedup vs baseline: 2.3422x; 2.3422x over previous
//
#include <hip/hip_runtime.h>

#define DD 128
#define NN 512
#define NODES 1024
#define TILE 64

typedef short bf16x8 __attribute__((ext_vector_type(8)));
typedef float f32x4 __attribute__((ext_vector_type(4)));

__device__ __forceinline__ float sigmoidf_(float x) { return 1.f / (1.f + __expf(-x)); }
__device__ __forceinline__ float siluf_(float x)    { return x / (1.f + __expf(-x)); }

__device__ __forceinline__ unsigned short f2bf_(float v) {
  unsigned int u = __float_as_uint(v);
  u += 0x7fffu + ((u >> 16) & 1u);   // RNE
  return (unsigned short)(u >> 16);
}
__device__ __forceinline__ float bflo_(unsigned u) { return __uint_as_float(u << 16); }
__device__ __forceinline__ float bfhi_(unsigned u) { return __uint_as_float(u & 0xffff0000u); }

// ---------------- prep kernel ----------------
__global__ __launch_bounds__(128) void prep_kernel(
    const float* __restrict__ sf, const float* __restrict__ cons,
    const float* __restrict__ eW1, const float* __restrict__ eb1,
    const float* __restrict__ eW2, const float* __restrict__ eb2,
    const float* __restrict__ vW1, const float* __restrict__ vb1,
    float* __restrict__ Ag, float* __restrict__ Bvg,
    unsigned short* __restrict__ E2V1T, float* __restrict__ m2,
    float* __restrict__ c1, float* __restrict__ mb)
{
  const int bid = blockIdx.x;
  const int d = threadIdx.x;
  if (bid < NODES) {
    float c = cons[bid];
    float aacc = c * eW1[258*DD + d];
    float bacc = eb1[d] + c * eW1[257*DD + d];
    const float* sfrow = sf + bid*DD;
    #pragma unroll 4
    for (int k = 0; k < DD; ++k) {
      float s = sfrow[k];
      aacc = fmaf(s, eW1[(128+k)*DD + d], aacc);
      bacc = fmaf(s, eW1[k*DD + d], bacc);
    }
    Ag[bid*DD + d]  = aacc;
    Bvg[bid*DD + d] = bacc;
  } else if (bid < NODES + 128) {
    // E2V1T[d][k] = sum_t eW2[k,t]*vW1[t,d], bf16, k pre-swizzled for MFMA B-frag reads
    const int k = bid - NODES;
    float acc = 0.f;
    #pragma unroll 4
    for (int t = 0; t < DD; ++t) acc = fmaf(eW2[k*DD + t], vW1[t*DD + d], acc);
    E2V1T[d*DD + (k ^ ((d & 7) << 3))] = f2bf_(acc);
    if (d == 0) {
      float s = 0.f;
      for (int t = 0; t < DD; ++t) s += eW2[k*DD + t];
      m2[k] = s * (1.0f/128.0f);
    }
  } else {
    float acc = vb1[d];
    #pragma unroll 4
    for (int k = 0; k < DD; ++k) acc = fmaf(eb2[k], vW1[k*DD + d], acc);
    c1[d] = acc;
    if (d == 0) {
      float s = 0.f;
      for (int k = 0; k < DD; ++k) s += eb2[k];
      mb[0] = s * (1.0f/128.0f);
    }
  }
}

// ---------------- main kernel: one block per (b,i) ----------------
__global__ __launch_bounds__(256) void edge_kernel(
    const float* __restrict__ sf, const float* __restrict__ vf,
    const float* __restrict__ pos, const float* __restrict__ pm,
    const float* __restrict__ eW1,
    const float* __restrict__ eW2, const float* __restrict__ eb2,
    const float* __restrict__ sW1, const float* __restrict__ sb1,
    const float* __restrict__ sW2, const float* __restrict__ sb2,
    const float* __restrict__ vW2g, const float* __restrict__ vb2g,
    const float* __restrict__ lnw, const float* __restrict__ lnb,
    const float* __restrict__ Ag, const float* __restrict__ Bvg,
    const unsigned short* __restrict__ E2V1Tg, const float* __restrict__ m2g,
    const float* __restrict__ c1g, const float* __restrict__ mbg,
    float* __restrict__ sout, float* __restrict__ vout, float* __restrict__ ewout)
{
  __shared__ __align__(16) unsigned short eT[128*128];    // 32 KB, [d][k^swz]
  __shared__ __align__(16) unsigned short hbf[TILE*128];  // 16 KB, [j][k^swz]
  __shared__ float BvL[DD], w256L[DD], w259L[DD], m2L[DD];
  __shared__ float distA[NN], maskA[NN], wA[NN];
  __shared__ float dirA[NN][3];
  __shared__ float gpart[4][TILE];
  __shared__ float redS[4], redA[2], redB[2];

  const int tid = threadIdx.x;
  const int ni  = blockIdx.x;
  const int nb  = ni & ~(NN - 1);

  const int l   = tid & 63, w = tid >> 6;
  const int l15 = l & 15,  lg = l >> 4;
  const int d   = tid & 127, sub = tid >> 7;
  const int jl  = tid >> 2, part = tid & 3;

  // stage E2V1T (pre-swizzled bf16) into LDS: pure vector copy
  {
    const uint4* esrc = (const uint4*)E2V1Tg;
    uint4* edst = (uint4*)eT;
    #pragma unroll
    for (int it = 0; it < 8; ++it) edst[tid + it*256] = esrc[tid + it*256];
  }
  if (tid < 128) {
    BvL[tid]   = Bvg[(size_t)ni*DD + tid];
    w256L[tid] = eW1[256*DD + tid];
    w259L[tid] = eW1[259*DD + tid];
    m2L[tid]   = m2g[tid];
  }
  // geometry for all 512 j (pos_i via uniform scalar loads)
  {
    float pix = pos[ni*3+0], piy = pos[ni*3+1], piz = pos[ni*3+2];
    #pragma unroll
    for (int rep = 0; rep < 2; ++rep) {
      int j = tid + rep*256;
      float rx = pix - pos[(nb + j)*3 + 0];
      float ry = piy - pos[(nb + j)*3 + 1];
      float rz = piz - pos[(nb + j)*3 + 2];
      float dist = fmaxf(sqrtf(rx*rx + ry*ry + rz*rz), 1e-8f);
      distA[j] = dist;
      float inv = 1.f / dist;
      dirA[j][0] = rx*inv; dirA[j][1] = ry*inv; dirA[j][2] = rz*inv;
      maskA[j] = pm[(size_t)ni*NN + j];
    }
  }

  float c1r2[2], vw2r2[2];
  #pragma unroll
  for (int ct = 0; ct < 2; ++ct) {
    int dc = w*32 + ct*16 + l15;
    c1r2[ct] = c1g[dc]; vw2r2[ct] = vW2g[dc];
  }
  const float mbv = mbg[0], vb2v = vb2g[0];

  float Sreg = 0.f;
  float vmx = 0.f, vmy = 0.f, vmz = 0.f;   // wave-0 vector-message accum

  for (int tile = 0; tile < 8; ++tile) {
    const int jt0 = tile * TILE;
    __syncthreads();   // protect hbf/gpart from previous iteration's readers
    // ---- A1: h = silu(Bv_i + A_j + dist*w256 + mask*w259) -> bf16 swizzled
    #pragma unroll
    for (int it = 0; it < 32; ++it) {
      int e = it*256 + tid;
      int j = e >> 7, dd = e & 127;
      float pre = BvL[dd] + Ag[(size_t)(nb + jt0 + j)*DD + dd]
                + distA[jt0 + j]*w256L[dd] + maskA[jt0 + j]*w259L[dd];
      hbf[j*128 + (dd ^ ((j & 7) << 3))] = f2bf_(siluf_(pre));
    }
    __syncthreads();
    // ---- A2: edge weights (all threads, jl in [0,64), part in [0,4))
    {
      float psum = 0.f;
      const int srow = (jl & 7) << 3;
      const unsigned short* hrow = &hbf[jl*128];
      #pragma unroll
      for (int q = 0; q < 4; ++q) {
        int b = part*32 + q*8;
        uint4 rv = *(const uint4*)(hrow + (b ^ srow));
        psum = fmaf(bflo_(rv.x), m2L[b+0], psum); psum = fmaf(bfhi_(rv.x), m2L[b+1], psum);
        psum = fmaf(bflo_(rv.y), m2L[b+2], psum); psum = fmaf(bfhi_(rv.y), m2L[b+3], psum);
        psum = fmaf(bflo_(rv.z), m2L[b+4], psum); psum = fmaf(bfhi_(rv.z), m2L[b+5], psum);
        psum = fmaf(bflo_(rv.w), m2L[b+6], psum); psum = fmaf(bfhi_(rv.w), m2L[b+7], psum);
      }
      psum += __shfl_xor(psum, 1);
      psum += __shfl_xor(psum, 2);
      if (part == 0) {
        float w_ = maskA[jt0 + jl] * sigmoidf_(psum + mbv);
        wA[jt0 + jl] = w_;
        ewout[(size_t)ni*NN + jt0 + jl] = w_;
      }
    }
    // ---- B: G1pre[64j][128d] = H @ E2V1 via MFMA; wave w owns cols [w*32, w*32+32)
    {
      f32x4 cfr[4][2];
      #pragma unroll
      for (int mt = 0; mt < 4; ++mt) {
        cfr[mt][0] = (f32x4){0.f,0.f,0.f,0.f};
        cfr[mt][1] = (f32x4){0.f,0.f,0.f,0.f};
      }
      #pragma unroll
      for (int kk = 0; kk < 4; ++kk) {
        const int kb = kk*32 + lg*8;
        bf16x8 bfrag[2];
        #pragma unroll
        for (int ct = 0; ct < 2; ++ct) {
          int col = w*32 + ct*16 + l15;
          bfrag[ct] = *(const bf16x8*)&eT[col*128 + (kb ^ ((col & 7) << 3))];
        }
        #pragma unroll
        for (int mt = 0; mt < 4; ++mt) {
          int row = mt*16 + l15;
          bf16x8 afrag = *(const bf16x8*)&hbf[row*128 + (kb ^ ((row & 7) << 3))];
          cfr[mt][0] = __builtin_amdgcn_mfma_f32_16x16x32_bf16(afrag, bfrag[0], cfr[mt][0], 0, 0, 0);
          cfr[mt][1] = __builtin_amdgcn_mfma_f32_16x16x32_bf16(afrag, bfrag[1], cfr[mt][1], 0, 0, 0);
        }
      }
      // gate partials over this wave's 32 d-cols; reduce over lanes l15
      #pragma unroll
      for (int mt = 0; mt < 4; ++mt) {
        #pragma unroll
        for (int r = 0; r < 4; ++r) {
          float v0 = siluf_(cfr[mt][0][r] + c1r2[0]) * vw2r2[0]
                   + siluf_(cfr[mt][1][r] + c1r2[1]) * vw2r2[1];
          v0 += __shfl_xor(v0, 1);
          v0 += __shfl_xor(v0, 2);
          v0 += __shfl_xor(v0, 4);
          v0 += __shfl_xor(v0, 8);
          if (l15 == 0) gpart[w][mt*16 + lg*4 + r] = v0;
        }
      }
    }
    __syncthreads();
    // ---- region 3: wave 0 finalizes gates + vector message; all threads do S accum
    if (w == 0) {
      int j = l;
      float g = (gpart[0][j] + gpart[1][j] + gpart[2][j] + gpart[3][j] + vb2v) * wA[jt0 + j];
      vmx = fmaf(g, dirA[jt0 + j][0], vmx);
      vmy = fmaf(g, dirA[jt0 + j][1], vmy);
      vmz = fmaf(g, dirA[jt0 + j][2], vmz);
    }
    #pragma unroll
    for (int r = 0; r < 32; ++r) {
      int j = sub*32 + r;
      unsigned short hv = hbf[j*128 + (d ^ ((j & 7) << 3))];
      Sreg = fmaf(wA[jt0 + j], __uint_as_float((unsigned)hv << 16), Sreg);
    }
  }

  // -------- epilogue --------
  __syncthreads();
  float* scr   = (float*)hbf;      // hbf no longer needed
  float* SL    = scr;
  float* partA = scr + 128;
  float* msgL  = scr + 256;
  float* u1L   = scr + 384;
  float* xoL   = scr + 512;

  // sum of edge weights
  {
    float sw = wA[tid] + wA[tid + 256];
    #pragma unroll
    for (int off = 1; off < 64; off <<= 1) sw += __shfl_xor(sw, off);
    if (l == 0) redS[w] = sw;
  }
  // vector message reduce (wave 0)
  if (w == 0) {
    #pragma unroll
    for (int off = 1; off < 64; off <<= 1) {
      vmx += __shfl_xor(vmx, off);
      vmy += __shfl_xor(vmy, off);
      vmz += __shfl_xor(vmz, off);
    }
  }
  if (sub == 0) SL[d] = Sreg;
  __syncthreads();
  if (sub == 1) SL[d] += Sreg;
  if (tid == 0) {
    vout[ni*3 + 0] = vf[ni*3 + 0] + vmx;
    vout[ni*3 + 1] = vf[ni*3 + 1] + vmy;
    vout[ni*3 + 2] = vf[ni*3 + 2] + vmz;
  }
  __syncthreads();
  const float sumwv = redS[0] + redS[1] + redS[2] + redS[3];

  // message_scalar = S@eW2 + sumw*eb2
  float p = 0.f;
  { int k0 = sub*64;
    #pragma unroll 4
    for (int k = k0; k < k0 + 64; ++k) p = fmaf(SL[k], eW2[k*DD + d], p); }
  if (sub) partA[d] = p;
  __syncthreads();
  if (!sub) msgL[d] = p + partA[d] + sumwv * eb2[d];
  __syncthreads();

  // u1 = silu([x, msg] @ sW1 + sb1)
  float q = 0.f;
  if (!sub) {
    const float* xr = sf + (size_t)ni*DD;
    #pragma unroll 4
    for (int t = 0; t < 128; ++t) q = fmaf(xr[t], sW1[t*DD + d], q);
  } else {
    #pragma unroll 4
    for (int t = 0; t < 128; ++t) q = fmaf(msgL[t], sW1[(128 + t)*DD + d], q);
  }
  if (sub) partA[d] = q;
  __syncthreads();
  if (!sub) u1L[d] = siluf_(q + partA[d] + sb1[d]);
  __syncthreads();

  // upd = u1 @ sW2 + sb2; x = sf + upd
  float r2 = 0.f;
  { int t0 = sub*64;
    #pragma unroll 4
    for (int t = t0; t < t0 + 64; ++t) r2 = fmaf(u1L[t], sW2[t*DD + d], r2); }
  if (sub) partA[d] = r2;
  __syncthreads();
  if (!sub) xoL[d] = sf[(size_t)ni*DD + d] + r2 + partA[d] + sb2[d];
  __syncthreads();

  // LayerNorm
  if (tid < 128) {
    float v = xoL[tid];
    float s1 = v, s2 = v*v;
    #pragma unroll
    for (int off = 1; off < 64; off <<= 1) { s1 += __shfl_xor(s1, off); s2 += __shfl_xor(s2, off); }
    if ((tid & 63) == 0) { redA[tid >> 6] = s1; redB[tid >> 6] = s2; }
  }
  __syncthreads();
  if (tid < 128) {
    float s1 = redA[0] + redA[1], s2 = redB[0] + redB[1];
    float mu = s1 * 0.0078125f;
    float var = s2 * 0.0078125f - mu*mu;
    sout[(size_t)ni*DD + tid] = (xoL[tid] - mu) * rsqrtf(var + 1e-5f) * lnw[tid] + lnb[tid];
  }
}

extern "C" void kernel_launch(void* const* d_in, const int* in_sizes, int n_in,
                              void* d_out, int out_size, void* d_ws, size_t ws_size,
                              hipStream_t stream) {
  const float* sf   = (const float*)d_in[0];
  const float* vf   = (const float*)d_in[1];
  const float* pos  = (const float*)d_in[2];
  const float* pm   = (const float*)d_in[3];
  const float* cons = (const float*)d_in[4];
  const float* eW1  = (const float*)d_in[5];
  const float* eb1  = (const float*)d_in[6];
  const float* eW2  = (const float*)d_in[7];
  const float* eb2  = (const float*)d_in[8];
  const float* sW1  = (const float*)d_in[9];
  const float* sb1  = (const float*)d_in[10];
  const float* sW2  = (const float*)d_in[11];
  const float* sb2  = (const float*)d_in[12];
  const float* vW1  = (const float*)d_in[13];
  const float* vb1  = (const float*)d_in[14];
  const float* vW2  = (const float*)d_in[15];
  const float* vb2  = (const float*)d_in[16];
  const float* lnw  = (const float*)d_in[17];
  const float* lnb  = (const float*)d_in[18];

  float* ws   = (float*)d_ws;
  float* Ag   = ws;                              // 1024*128 f32
  float* Bvg  = ws + 131072;                     // 1024*128 f32
  float* m2   = ws + 262144;                     // 128
  float* c1   = ws + 262272;                     // 128
  float* mb   = ws + 262400;                     // 1
  unsigned short* E2V1T = (unsigned short*)(ws + 262402); // 128*128 bf16

  float* sout  = (float*)d_out;      // [2,512,128]
  float* vout  = sout + 131072;      // [2,512,3]
  float* ewout = sout + 134144;      // [2,512,512]

  hipLaunchKernelGGL(prep_kernel, dim3(NODES + 129), dim3(128), 0, stream,
                     sf, cons, eW1, eb1, eW2, eb2, vW1, vb1,
                     Ag, Bvg, E2V1T, m2, c1, mb);
  hipLaunchKernelGGL(edge_kernel, dim3(NODES), dim3(256), 0, stream,
                     sf, vf, pos, pm, eW1, eW2, eb2, sW1, sb1, sW2, sb2,
                     vW2, vb2, lnw, lnb, Ag, Bvg, E2V1T, m2, c1, mb,
                     sout, vout, ewout);
}

// Round 3
// 101.283 us; speedup vs baseline: 4.0447x; 1.7269x over previous
//
#include <hip/hip_runtime.h>

#define DD 128
#define NN 512
#define NODES 1024
#define TILE 64

typedef short bf16x8 __attribute__((ext_vector_type(8)));
typedef float f32x4 __attribute__((ext_vector_type(4)));

__device__ __forceinline__ float sigmoidf_(float x) {
  return __builtin_amdgcn_rcpf(1.f + __expf(-x));
}
__device__ __forceinline__ float siluf_(float x) { return x * sigmoidf_(x); }

__device__ __forceinline__ unsigned short f2bf_(float v) {
  unsigned int u = __float_as_uint(v);
  u += 0x7fffu + ((u >> 16) & 1u);   // RNE
  return (unsigned short)(u >> 16);
}
__device__ __forceinline__ unsigned cvtpk_(float lo, float hi) {
  unsigned r;
  asm("v_cvt_pk_bf16_f32 %0, %1, %2" : "=v"(r) : "v"(lo), "v"(hi));
  return r;
}
__device__ __forceinline__ float bflo_(unsigned u) { return __uint_as_float(u << 16); }
__device__ __forceinline__ float bfhi_(unsigned u) { return __uint_as_float(u & 0xffff0000u); }

// ---------------- prep kernel ----------------
__global__ __launch_bounds__(128) void prep_kernel(
    const float* __restrict__ sf, const float* __restrict__ cons,
    const float* __restrict__ eW1, const float* __restrict__ eb1,
    const float* __restrict__ eW2, const float* __restrict__ eb2,
    const float* __restrict__ vW1, const float* __restrict__ vb1,
    float* __restrict__ Ag, float* __restrict__ Bvg,
    unsigned short* __restrict__ E2V1T, float* __restrict__ m2,
    float* __restrict__ c1, float* __restrict__ mb)
{
  const int bid = blockIdx.x;
  const int d = threadIdx.x;
  if (bid < NODES) {
    float c = cons[bid];
    float aacc = c * eW1[258*DD + d];
    float bacc = eb1[d] + c * eW1[257*DD + d];
    const float* sfrow = sf + bid*DD;
    #pragma unroll 4
    for (int k = 0; k < DD; ++k) {
      float s = sfrow[k];
      aacc = fmaf(s, eW1[(128+k)*DD + d], aacc);
      bacc = fmaf(s, eW1[k*DD + d], bacc);
    }
    Ag[bid*DD + d]  = aacc;
    Bvg[bid*DD + d] = bacc;
  } else if (bid < NODES + 128) {
    // E2V1T[d][k] = sum_t eW2[k,t]*vW1[t,d]  (bf16, plain layout)
    const int k = bid - NODES;
    float acc = 0.f;
    #pragma unroll 4
    for (int t = 0; t < DD; ++t) acc = fmaf(eW2[k*DD + t], vW1[t*DD + d], acc);
    E2V1T[d*DD + k] = f2bf_(acc);
    if (d == 0) {
      float s = 0.f;
      for (int t = 0; t < DD; ++t) s += eW2[k*DD + t];
      m2[k] = s * (1.0f/128.0f);
    }
  } else {
    float acc = vb1[d];
    #pragma unroll 4
    for (int k = 0; k < DD; ++k) acc = fmaf(eb2[k], vW1[k*DD + d], acc);
    c1[d] = acc;
    if (d == 0) {
      float s = 0.f;
      for (int k = 0; k < DD; ++k) s += eb2[k];
      mb[0] = s * (1.0f/128.0f);
    }
  }
}

// ---------------- main kernel: one block per (b,i) ----------------
__global__ __launch_bounds__(256, 4) void edge_kernel(
    const float* __restrict__ sf, const float* __restrict__ vf,
    const float* __restrict__ pos, const float* __restrict__ pm,
    const float* __restrict__ eW1,
    const float* __restrict__ eW2, const float* __restrict__ eb2,
    const float* __restrict__ sW1, const float* __restrict__ sb1,
    const float* __restrict__ sW2, const float* __restrict__ sb2,
    const float* __restrict__ vW2g, const float* __restrict__ vb2g,
    const float* __restrict__ lnw, const float* __restrict__ lnb,
    const float* __restrict__ Ag, const float* __restrict__ Bvg,
    const unsigned short* __restrict__ E2V1Tg, const float* __restrict__ m2g,
    const float* __restrict__ c1g, const float* __restrict__ mbg,
    float* __restrict__ sout, float* __restrict__ vout, float* __restrict__ ewout)
{
  __shared__ __align__(16) unsigned short hbf[TILE*128];  // 16 KB, [j][k^swz]
  __shared__ __align__(16) float BvL[DD], w256L[DD], w259L[DD], m2L[DD];
  __shared__ float distA[NN], maskA[NN], wA[NN];
  __shared__ float dirA[NN][3];
  __shared__ float gpart[4][TILE];
  __shared__ float redS[4], redA[2], redB[2];

  const int tid = threadIdx.x;
  const int ni  = blockIdx.x;
  const int nb  = ni & ~(NN - 1);

  const int l   = tid & 63, w = tid >> 6;
  const int l15 = l & 15,  lg = l >> 4;
  const int d   = tid & 127, sub = tid >> 7;
  const int g16 = tid >> 4, db = (tid & 15) * 8;

  if (tid < 128) {
    BvL[tid]   = Bvg[(size_t)ni*DD + tid];
    w256L[tid] = eW1[256*DD + tid];
    w259L[tid] = eW1[259*DD + tid];
    m2L[tid]   = m2g[tid];
  }
  // geometry for all 512 j
  {
    float pix = pos[ni*3+0], piy = pos[ni*3+1], piz = pos[ni*3+2];
    #pragma unroll
    for (int rep = 0; rep < 2; ++rep) {
      int j = tid + rep*256;
      float rx = pix - pos[(nb + j)*3 + 0];
      float ry = piy - pos[(nb + j)*3 + 1];
      float rz = piz - pos[(nb + j)*3 + 2];
      float dist = fmaxf(sqrtf(rx*rx + ry*ry + rz*rz), 1e-8f);
      distA[j] = dist;
      float inv = __builtin_amdgcn_rcpf(dist);
      dirA[j][0] = rx*inv; dirA[j][1] = ry*inv; dirA[j][2] = rz*inv;
      maskA[j] = pm[(size_t)ni*NN + j];
    }
  }

  float c1r2[2], vw2r2[2];
  #pragma unroll
  for (int ct = 0; ct < 2; ++ct) {
    int dc = w*32 + ct*16 + l15;
    c1r2[ct] = c1g[dc]; vw2r2[ct] = vW2g[dc];
  }
  const float mbv = mbg[0], vb2v = vb2g[0];

  float Sreg8[8];
  #pragma unroll
  for (int m = 0; m < 8; ++m) Sreg8[m] = 0.f;
  float vmx = 0.f, vmy = 0.f, vmz = 0.f;

  for (int tile = 0; tile < 8; ++tile) {
    const int jt0 = tile * TILE;
    __syncthreads();   // guard hbf/wA reuse
    // ---- A1+A2 fused: h = silu(pre) -> hbf; edge weight via in-reg dot ----
    {
      float4 bv0 = *(const float4*)&BvL[db],   bv1 = *(const float4*)&BvL[db+4];
      float4 wa0 = *(const float4*)&w256L[db], wa1 = *(const float4*)&w256L[db+4];
      float4 wb0 = *(const float4*)&w259L[db], wb1 = *(const float4*)&w259L[db+4];
      float4 m20 = *(const float4*)&m2L[db],   m21 = *(const float4*)&m2L[db+4];
      #pragma unroll
      for (int it = 0; it < 4; ++it) {
        int j = it*16 + g16;
        int jj = jt0 + j;
        const float4* ag = (const float4*)&Ag[(size_t)(nb + jj)*DD + db];
        float4 a0 = ag[0], a1 = ag[1];
        float dj = distA[jj], mj = maskA[jj];
        float h0 = siluf_(bv0.x + a0.x + dj*wa0.x + mj*wb0.x);
        float h1 = siluf_(bv0.y + a0.y + dj*wa0.y + mj*wb0.y);
        float h2 = siluf_(bv0.z + a0.z + dj*wa0.z + mj*wb0.z);
        float h3 = siluf_(bv0.w + a0.w + dj*wa0.w + mj*wb0.w);
        float h4 = siluf_(bv1.x + a1.x + dj*wa1.x + mj*wb1.x);
        float h5 = siluf_(bv1.y + a1.y + dj*wa1.y + mj*wb1.y);
        float h6 = siluf_(bv1.z + a1.z + dj*wa1.z + mj*wb1.z);
        float h7 = siluf_(bv1.w + a1.w + dj*wa1.w + mj*wb1.w);
        uint4 pk;
        pk.x = cvtpk_(h0, h1); pk.y = cvtpk_(h2, h3);
        pk.z = cvtpk_(h4, h5); pk.w = cvtpk_(h6, h7);
        *(uint4*)&hbf[j*128 + (db ^ ((j & 7) << 3))] = pk;
        float psum = h0*m20.x + h1*m20.y + h2*m20.z + h3*m20.w
                   + h4*m21.x + h5*m21.y + h6*m21.z + h7*m21.w;
        psum += __shfl_xor(psum, 1);
        psum += __shfl_xor(psum, 2);
        psum += __shfl_xor(psum, 4);
        psum += __shfl_xor(psum, 8);
        if ((tid & 15) == 0) {
          float w_ = mj * sigmoidf_(psum + mbv);
          wA[jj] = w_;
          ewout[(size_t)ni*NN + jj] = w_;
        }
      }
    }
    __syncthreads();
    // ---- B: G1pre = H @ E2V1 via MFMA; wave w owns d-cols [w*32, w*32+32) ----
    {
      f32x4 cfr[4][2];
      #pragma unroll
      for (int mt = 0; mt < 4; ++mt) {
        cfr[mt][0] = (f32x4){0.f,0.f,0.f,0.f};
        cfr[mt][1] = (f32x4){0.f,0.f,0.f,0.f};
      }
      #pragma unroll
      for (int kk = 0; kk < 4; ++kk) {
        const int kb = kk*32 + lg*8;
        bf16x8 bf0 = *(const bf16x8*)&E2V1Tg[(size_t)(w*32 + l15)*128 + kb];
        bf16x8 bf1 = *(const bf16x8*)&E2V1Tg[(size_t)(w*32 + 16 + l15)*128 + kb];
        #pragma unroll
        for (int mt = 0; mt < 4; ++mt) {
          int row = mt*16 + l15;
          bf16x8 af = *(const bf16x8*)&hbf[row*128 + (kb ^ ((row & 7) << 3))];
          cfr[mt][0] = __builtin_amdgcn_mfma_f32_16x16x32_bf16(af, bf0, cfr[mt][0], 0, 0, 0);
          cfr[mt][1] = __builtin_amdgcn_mfma_f32_16x16x32_bf16(af, bf1, cfr[mt][1], 0, 0, 0);
        }
      }
      // gate partials over this wave's 32 d-cols; reduce over l15
      #pragma unroll
      for (int mt = 0; mt < 4; ++mt) {
        #pragma unroll
        for (int r = 0; r < 4; ++r) {
          float v0 = siluf_(cfr[mt][0][r] + c1r2[0]) * vw2r2[0]
                   + siluf_(cfr[mt][1][r] + c1r2[1]) * vw2r2[1];
          v0 += __shfl_xor(v0, 1);
          v0 += __shfl_xor(v0, 2);
          v0 += __shfl_xor(v0, 4);
          v0 += __shfl_xor(v0, 8);
          if (l15 == 0) gpart[w][mt*16 + lg*4 + r] = v0;
        }
      }
    }
    __syncthreads();
    // ---- region 3: wave 0 finalizes gates + vector message; all do S accum ----
    if (w == 0) {
      int j = l;
      float g = (gpart[0][j] + gpart[1][j] + gpart[2][j] + gpart[3][j] + vb2v) * wA[jt0 + j];
      vmx = fmaf(g, dirA[jt0 + j][0], vmx);
      vmy = fmaf(g, dirA[jt0 + j][1], vmy);
      vmz = fmaf(g, dirA[jt0 + j][2], vmz);
    }
    #pragma unroll
    for (int r = 0; r < 4; ++r) {
      int j = g16*4 + r;
      float wj = wA[jt0 + j];
      uint4 hv = *(const uint4*)&hbf[j*128 + (db ^ ((j & 7) << 3))];
      Sreg8[0] = fmaf(wj, bflo_(hv.x), Sreg8[0]);
      Sreg8[1] = fmaf(wj, bfhi_(hv.x), Sreg8[1]);
      Sreg8[2] = fmaf(wj, bflo_(hv.y), Sreg8[2]);
      Sreg8[3] = fmaf(wj, bfhi_(hv.y), Sreg8[3]);
      Sreg8[4] = fmaf(wj, bflo_(hv.z), Sreg8[4]);
      Sreg8[5] = fmaf(wj, bfhi_(hv.z), Sreg8[5]);
      Sreg8[6] = fmaf(wj, bflo_(hv.w), Sreg8[6]);
      Sreg8[7] = fmaf(wj, bfhi_(hv.w), Sreg8[7]);
    }
  }

  // -------- epilogue --------
  float* scr   = (float*)hbf;
  float* Spart = scr;          // [4][128]
  float* SL    = scr + 512;
  float* partA = scr + 640;
  float* msgL  = scr + 768;
  float* u1L   = scr + 896;
  float* xoL   = scr + 1024;

  __syncthreads();             // all S-accum reads of hbf done
  #pragma unroll
  for (int m = 0; m < 8; ++m) {
    float s = Sreg8[m];
    s += __shfl_xor(s, 16);
    s += __shfl_xor(s, 32);
    if (l < 16) Spart[w*128 + l*8 + m] = s;
  }
  {
    float sw = wA[tid] + wA[tid + 256];
    #pragma unroll
    for (int off = 1; off < 64; off <<= 1) sw += __shfl_xor(sw, off);
    if (l == 0) redS[w] = sw;
  }
  if (w == 0) {
    #pragma unroll
    for (int off = 1; off < 64; off <<= 1) {
      vmx += __shfl_xor(vmx, off);
      vmy += __shfl_xor(vmy, off);
      vmz += __shfl_xor(vmz, off);
    }
    if (l == 0) {
      vout[ni*3 + 0] = vf[ni*3 + 0] + vmx;
      vout[ni*3 + 1] = vf[ni*3 + 1] + vmy;
      vout[ni*3 + 2] = vf[ni*3 + 2] + vmz;
    }
  }
  __syncthreads();
  if (tid < 128) SL[tid] = Spart[tid] + Spart[128 + tid] + Spart[256 + tid] + Spart[384 + tid];
  __syncthreads();
  const float sumwv = redS[0] + redS[1] + redS[2] + redS[3];

  // message_scalar = S@eW2 + sumw*eb2
  float p = 0.f;
  { int k0 = sub*64;
    #pragma unroll 4
    for (int k = k0; k < k0 + 64; ++k) p = fmaf(SL[k], eW2[k*DD + d], p); }
  if (sub) partA[d] = p;
  __syncthreads();
  if (!sub) msgL[d] = p + partA[d] + sumwv * eb2[d];
  __syncthreads();

  // u1 = silu([x, msg] @ sW1 + sb1)
  float q = 0.f;
  if (!sub) {
    const float* xr = sf + (size_t)ni*DD;
    #pragma unroll 4
    for (int t = 0; t < 128; ++t) q = fmaf(xr[t], sW1[t*DD + d], q);
  } else {
    #pragma unroll 4
    for (int t = 0; t < 128; ++t) q = fmaf(msgL[t], sW1[(128 + t)*DD + d], q);
  }
  if (sub) partA[d] = q;
  __syncthreads();
  if (!sub) u1L[d] = siluf_(q + partA[d] + sb1[d]);
  __syncthreads();

  // upd = u1 @ sW2 + sb2; x = sf + upd
  float r2 = 0.f;
  { int t0 = sub*64;
    #pragma unroll 4
    for (int t = t0; t < t0 + 64; ++t) r2 = fmaf(u1L[t], sW2[t*DD + d], r2); }
  if (sub) partA[d] = r2;
  __syncthreads();
  if (!sub) xoL[d] = sf[(size_t)ni*DD + d] + r2 + partA[d] + sb2[d];
  __syncthreads();

  // LayerNorm
  if (tid < 128) {
    float v = xoL[tid];
    float s1 = v, s2 = v*v;
    #pragma unroll
    for (int off = 1; off < 64; off <<= 1) { s1 += __shfl_xor(s1, off); s2 += __shfl_xor(s2, off); }
    if ((tid & 63) == 0) { redA[tid >> 6] = s1; redB[tid >> 6] = s2; }
  }
  __syncthreads();
  if (tid < 128) {
    float s1 = redA[0] + redA[1], s2 = redB[0] + redB[1];
    float mu = s1 * 0.0078125f;
    float var = s2 * 0.0078125f - mu*mu;
    sout[(size_t)ni*DD + tid] = (xoL[tid] - mu) * rsqrtf(var + 1e-5f) * lnw[tid] + lnb[tid];
  }
}

extern "C" void kernel_launch(void* const* d_in, const int* in_sizes, int n_in,
                              void* d_out, int out_size, void* d_ws, size_t ws_size,
                              hipStream_t stream) {
  const float* sf   = (const float*)d_in[0];
  const float* vf   = (const float*)d_in[1];
  const float* pos  = (const float*)d_in[2];
  const float* pm   = (const float*)d_in[3];
  const float* cons = (const float*)d_in[4];
  const float* eW1  = (const float*)d_in[5];
  const float* eb1  = (const float*)d_in[6];
  const float* eW2  = (const float*)d_in[7];
  const float* eb2  = (const float*)d_in[8];
  const float* sW1  = (const float*)d_in[9];
  const float* sb1  = (const float*)d_in[10];
  const float* sW2  = (const float*)d_in[11];
  const float* sb2  = (const float*)d_in[12];
  const float* vW1  = (const float*)d_in[13];
  const float* vb1  = (const float*)d_in[14];
  const float* vW2  = (const float*)d_in[15];
  const float* vb2  = (const float*)d_in[16];
  const float* lnw  = (const float*)d_in[17];
  const float* lnb  = (const float*)d_in[18];

  float* ws   = (float*)d_ws;
  float* Ag   = ws;                              // 1024*128 f32
  float* Bvg  = ws + 131072;                     // 1024*128 f32
  float* m2   = ws + 262144;                     // 128
  float* c1   = ws + 262272;                     // 128
  float* mb   = ws + 262400;                     // 1 (+pad)
  unsigned short* E2V1T = (unsigned short*)(ws + 262404); // 128*128 bf16, 16B-aligned

  float* sout  = (float*)d_out;      // [2,512,128]
  float* vout  = sout + 131072;      // [2,512,3]
  float* ewout = sout + 134144;      // [2,512,512]

  hipLaunchKernelGGL(prep_kernel, dim3(NODES + 129), dim3(128), 0, stream,
                     sf, cons, eW1, eb1, eW2, eb2, vW1, vb1,
                     Ag, Bvg, E2V1T, m2, c1, mb);
  hipLaunchKernelGGL(edge_kernel, dim3(NODES), dim3(256), 0, stream,
                     sf, vf, pos, pm, eW1, eW2, eb2, sW1, sb1, sW2, sb2,
                     vW2, vb2, lnw, lnb, Ag, Bvg, E2V1T, m2, c1, mb,
                     sout, vout, ewout);
}